// Round 16
// baseline (765.719 us; speedup 1.0000x reference)
//
#include <hip/hip_runtime.h>
#include <hip/hip_bf16.h>
#include <cstdint>
#include <cstddef>

typedef __bf16 bf16;
typedef __attribute__((ext_vector_type(8))) __bf16 bf16x8;
typedef __attribute__((ext_vector_type(2))) __bf16 bf16x2;
typedef __attribute__((ext_vector_type(4))) __bf16 bf16x4;
typedef __attribute__((ext_vector_type(4))) float f32x4;

#define DEVI __device__ __forceinline__

constexpr int Bb = 256, Nn = 164, NKk = 100;
constexpr int Mm = Bb * Nn;   // 41984 = 164 * 256
constexpr int JP = 192;

DEVI void gl_lds16(const void* g, void* l) {
  __builtin_amdgcn_global_load_lds(
      (const __attribute__((address_space(1))) void*)g,
      (__attribute__((address_space(3))) void*)l, 16, 0, 0);
}

DEVI int sw16(int row, int kb) { return row * 128 + ((kb ^ (row & 7)) * 8); }
DEVI int sw8(int row, int kb)  { return row * 64 + ((kb ^ (row & 7)) * 8); }

DEVI void barrier_raw() {
  asm volatile("" ::: "memory");
  __builtin_amdgcn_s_barrier();
  asm volatile("" ::: "memory");
}

// ---------------- convert f32 -> bf16 (flat) ----------------
__global__ void k_cvt_bf16(const float* __restrict__ in, bf16* __restrict__ out, int n) {
  int stride = gridDim.x * blockDim.x;
  for (int i = blockIdx.x * blockDim.x + threadIdx.x; i < (n >> 2); i += stride) {
    float4 v = ((const float4*)in)[i];
    bf16x4 o;
    o[0] = (bf16)v.x; o[1] = (bf16)v.y; o[2] = (bf16)v.z; o[3] = (bf16)v.w;
    ((bf16x4*)out)[i] = o;
  }
}

// ---------------- mask dtype detection ----------------
__global__ void k_maskdet(const unsigned char* __restrict__ m, int* __restrict__ mode) {
  __shared__ int sbyte, sodd;
  if (threadIdx.x == 0) { sbyte = 0; sodd = 0; }
  __syncthreads();
  for (int i = threadIdx.x; i < Mm; i += 256)
    if ((i & 3) && m[i]) sbyte = 1;
  __syncthreads();
  if (sbyte == 0) {
    const int* m32 = (const int*)m;
    for (int i = 1 + 2 * (int)threadIdx.x; i < Mm; i += 512)
      if (m32[i] != 0) sodd = 1;
  }
  __syncthreads();
  if (threadIdx.x == 0) *mode = sbyte ? 1 : (sodd ? 0 : 2);
}

// ---------------- prep: W1T/W2T swizzled bf16 LDS-images ----------------
__global__ void k_prep_w(const float* __restrict__ W1, const float* __restrict__ W2,
                         bf16* __restrict__ w1t, bf16* __restrict__ w2t) {
  int tid = threadIdx.x;
  int4 z = make_int4(0, 0, 0, 0);
  for (int i = tid; i < 1024; i += 256) ((int4*)w1t)[i] = z;  // 16384 B
  for (int i = tid; i < 896;  i += 256) ((int4*)w2t)[i] = z;  // 14336 B
  __syncthreads();
  for (int idx = tid; idx < 5000; idx += 256) {  // W1 [100][50] -> rows=c cols=k
    int k = idx / 50, c = idx % 50;
    w1t[sw16(c, k >> 3) + (k & 7)] = (bf16)W1[idx];
  }
  for (int idx = tid; idx < 5000; idx += 256) {  // W2 [50][100] -> rows=jp cols=c
    int c = idx / 100, jp = idx % 100;
    w2t[sw8(jp, c >> 3) + (c & 7)] = (bf16)W2[idx];
  }
}

// ---------------- prep: mask -> additive bias rows [256][192] f32 ----------------
__global__ void k_maskbias(const void* __restrict__ maskp, const int* __restrict__ mode,
                           float* __restrict__ mb) {
  int b = blockIdx.x, col = threadIdx.x;  // 192 threads
  int mmode = *mode;
  float v;
  if (col < NKk) v = 0.f;
  else if (col < 164) {
    int mi = b * 164 + col;
    long long m = (mmode == 1) ? (long long)((const unsigned char*)maskp)[mi]
                : (mmode == 0) ? (long long)((const int*)maskp)[mi]
                               : ((const long long*)maskp)[mi];
    v = m ? -__FLT_MAX__ : 0.f;
  } else v = -__FLT_MAX__;
  mb[b * 192 + col] = v;
}

// ---------------- prep: xian [b][gi][jp] -> xianT [b][jp][112-stride gi] ----------------
__global__ void k_xianT(const float* __restrict__ xian, float* __restrict__ xT) {
  __shared__ float t[32][33];
  int b = blockIdx.y;
  int gt = blockIdx.x & 3, jt = blockIdx.x >> 2;
  int tx = threadIdx.x & 31, ty = threadIdx.x >> 5;
#pragma unroll
  for (int i = 0; i < 4; ++i) {
    int gi = gt * 32 + ty + i * 8, jp = jt * 32 + tx;
    t[ty + i * 8][tx] = (gi < 100 && jp < 100) ? xian[((size_t)b * 100 + gi) * 100 + jp] : 0.f;
  }
  __syncthreads();
#pragma unroll
  for (int i = 0; i < 4; ++i) {
    int jp = jt * 32 + ty + i * 8, gi = gt * 32 + tx;
    if (jp < 100 && gi < 112)
      xT[((size_t)b * 100 + jp) * 112 + gi] = t[tx][ty + i * 8];
  }
}

// ---------------- transpose + convert: (R x C f32) -> (C x R bf16) ----------------
__global__ void k_transpose_cvt(const float* __restrict__ in, bf16* __restrict__ out,
                                int R, int C) {
  __shared__ float tile[32][33];
  int c0 = blockIdx.x * 32, r0 = blockIdx.y * 32;
  int tx = threadIdx.x & 31, ty = threadIdx.x >> 5;
#pragma unroll
  for (int i = 0; i < 4; ++i) {
    int r = ty + i * 8;
    tile[r][tx] = in[(size_t)(r0 + r) * C + c0 + tx];
  }
  __syncthreads();
#pragma unroll
  for (int i = 0; i < 4; ++i) {
    int rr = ty + i * 8;
    out[(size_t)(c0 + rr) * R + r0 + tx] = (bf16)tile[tx][rr];
  }
}

// ======== 256x256 GEMM, BK=32, triple-buffer, counted-vmcnt pipeline (T4) ========
// C(MxN) = A(MxK) * Bt(NxK)^T, K=1024. Loads for tile t+2 issue during tile t;
// top-of-tile wait = vmcnt(4) (drains tile t's 4 loads, keeps t+1's in flight);
// one raw s_barrier per tile (crossing it proves all prior-tile ds_reads done).
// MODE 0: C bf16 ld 3072; tileN>=2048 (V region) written TRANSPOSED into vT.
// MODE 1: C f32 + bias, ld 1024.
template <int MODE>
__global__ __launch_bounds__(512, 2) void k_gemm(const bf16* __restrict__ A,
                                                 const bf16* __restrict__ Bt,
                                                 void* __restrict__ Cout,
                                                 const float* __restrict__ bias,
                                                 bf16* __restrict__ vTout) {
  constexpr int K = 1024;
  constexpr int NT = 32;                       // K-tiles of 32
  __shared__ __align__(16) char smem[98304];   // 3 x (A 16KB | B 16KB)

  const int tid = threadIdx.x, lane = tid & 63, w = tid >> 6;
  const int l15 = lane & 15, l4 = lane >> 4;
  const int wm = w >> 2, wn = w & 3;

  const int nbx = (MODE == 0) ? 12 : 4;
  const int lin = blockIdx.x;
  const int cpx = gridDim.x >> 3;
  const int swz = (lin & 7) * cpx + (lin >> 3);
  const int tileM = (swz / nbx) * 256, tileN = (swz % nbx) * 256;

  // staging: per thread 2 A + 2 B chunks of 16B per K-tile
  size_t aoff[2], boff[2]; int loff[2];
#pragma unroll
  for (int li = 0; li < 2; ++li) {
    int idx = li * 512 + tid;            // 0..1023: row = idx>>2, granule = idx&3
    int row = idx >> 2, g = idx & 3;
    int kb = g ^ ((row >> 1) & 3);       // pre-swizzled global source granule
    aoff[li] = (size_t)(tileM + row) * K + kb * 8;
    boff[li] = (size_t)(tileN + row) * K + kb * 8;
    loff[li] = idx * 16;                 // linear LDS dest (bytes) within half
  }

  f32x4 acc[8][4];
#pragma unroll
  for (int mf = 0; mf < 8; ++mf)
#pragma unroll
    for (int nf = 0; nf < 4; ++nf) acc[mf][nf] = f32x4{0.f, 0.f, 0.f, 0.f};

  // prologue: stage tiles 0 and 1 (tile0's 4 loads oldest per thread)
#pragma unroll
  for (int tt = 0; tt < 2; ++tt)
#pragma unroll
    for (int li = 0; li < 2; ++li) {
      gl_lds16(A + aoff[li] + tt * 32, smem + tt * 32768 + loff[li]);
      gl_lds16(Bt + boff[li] + tt * 32, smem + tt * 32768 + 16384 + loff[li]);
    }

  int cur = 0;
  for (int t = 0; t < NT - 1; ++t) {
    const char* Ac = smem + cur * 32768;
    const char* Bc = Ac + 16384;
    asm volatile("s_waitcnt vmcnt(4)" ::: "memory");  // tile t landed; t+1 in flight
    __builtin_amdgcn_s_barrier();
    asm volatile("" ::: "memory");

    if (t + 2 < NT) {                   // issue tile t+2 into buffer (cur+2)%3
      int nb = cur + 2; if (nb >= 3) nb -= 3;
      char* Ln = smem + nb * 32768;
      const int kadd = (t + 2) * 32;
#pragma unroll
      for (int li = 0; li < 2; ++li) {
        gl_lds16(A + aoff[li] + kadd, Ln + loff[li]);
        gl_lds16(Bt + boff[li] + kadd, Ln + 16384 + loff[li]);
      }
    }

    bf16x8 bfr[4];
#pragma unroll
    for (int nf = 0; nf < 4; ++nf) {
      int row = wn * 64 + nf * 16 + l15;
      bfr[nf] = *(const bf16x8*)(Bc + row * 64 + ((l4 ^ ((row >> 1) & 3)) * 16));
    }
    bf16x8 af[8];
#pragma unroll
    for (int mf = 0; mf < 8; ++mf) {
      int row = wm * 128 + mf * 16 + l15;
      af[mf] = *(const bf16x8*)(Ac + row * 64 + ((l4 ^ ((row >> 1) & 3)) * 16));
    }
    __builtin_amdgcn_s_setprio(1);
#pragma unroll
    for (int mf = 0; mf < 8; ++mf)
#pragma unroll
      for (int nf = 0; nf < 4; ++nf)
        acc[mf][nf] = __builtin_amdgcn_mfma_f32_16x16x32_bf16(
            af[mf], bfr[nf], acc[mf][nf], 0, 0, 0);
    __builtin_amdgcn_s_setprio(0);

    cur = (cur + 1 == 3) ? 0 : cur + 1;
  }
  {  // peeled last tile: full drain
    const char* Ac = smem + cur * 32768;
    const char* Bc = Ac + 16384;
    asm volatile("s_waitcnt vmcnt(0)" ::: "memory");
    __builtin_amdgcn_s_barrier();
    asm volatile("" ::: "memory");
    bf16x8 bfr[4];
#pragma unroll
    for (int nf = 0; nf < 4; ++nf) {
      int row = wn * 64 + nf * 16 + l15;
      bfr[nf] = *(const bf16x8*)(Bc + row * 64 + ((l4 ^ ((row >> 1) & 3)) * 16));
    }
    bf16x8 af[8];
#pragma unroll
    for (int mf = 0; mf < 8; ++mf) {
      int row = wm * 128 + mf * 16 + l15;
      af[mf] = *(const bf16x8*)(Ac + row * 64 + ((l4 ^ ((row >> 1) & 3)) * 16));
    }
    __builtin_amdgcn_s_setprio(1);
#pragma unroll
    for (int mf = 0; mf < 8; ++mf)
#pragma unroll
      for (int nf = 0; nf < 4; ++nf)
        acc[mf][nf] = __builtin_amdgcn_mfma_f32_16x16x32_bf16(
            af[mf], bfr[nf], acc[mf][nf], 0, 0, 0);
    __builtin_amdgcn_s_setprio(0);
  }

  if (MODE == 0 && tileN >= 2048) {
    const int h0 = (tileN - 2048) >> 7;
    bf16* Et = (bf16*)smem;              // [128][264] bf16 = 67584 B <= 98304
#pragma unroll
    for (int nh = 0; nh < 2; ++nh) {
      barrier_raw();
      if ((wn >> 1) == nh) {
#pragma unroll
        for (int mf = 0; mf < 8; ++mf)
#pragma unroll
          for (int nf = 0; nf < 4; ++nf) {
            int nr = (wn & 1) * 64 + nf * 16 + l15;
            int mr = wm * 128 + mf * 16 + l4 * 4;
            bf16x4 pv;
#pragma unroll
            for (int j = 0; j < 4; ++j) pv[j] = (bf16)acc[mf][nf][j];
            *(bf16x4*)&Et[nr * 264 + mr] = pv;
          }
      }
      barrier_raw();
#pragma unroll
      for (int r8 = 0; r8 < 8; ++r8) {
        int idx = r8 * 512 + tid;
        int nr = idx >> 5, m8 = (idx & 31) * 8;
        bf16x8 v = *(const bf16x8*)&Et[nr * 264 + m8];
        int m = tileM + m8;
        int b = m / 164, j = m - b * 164;
        if (j + 7 < 164) {
          size_t base = ((size_t)(b * 8 + h0 + nh) * 128 + nr) * JP + j;
          bf16x4 lo, hi;
#pragma unroll
          for (int e = 0; e < 4; ++e) { lo[e] = v[e]; hi[e] = v[e + 4]; }
          *(bf16x4*)&vTout[base] = lo;
          *(bf16x4*)&vTout[base + 4] = hi;
        } else {
#pragma unroll
          for (int e = 0; e < 8; ++e) {
            int me = m + e; int be = me / 164, je = me - be * 164;
            vTout[((size_t)(be * 8 + h0 + nh) * 128 + nr) * JP + je] = v[e];
          }
        }
      }
    }
  } else {
#pragma unroll
    for (int mf = 0; mf < 8; ++mf)
#pragma unroll
      for (int nf = 0; nf < 4; ++nf) {
        int m0 = tileM + wm * 128 + mf * 16 + l4 * 4;
        int n = tileN + wn * 64 + nf * 16 + l15;
        if (MODE == 0) {
#pragma unroll
          for (int j = 0; j < 4; ++j)
            ((bf16*)Cout)[(size_t)(m0 + j) * 3072 + n] = (bf16)acc[mf][nf][j];
        } else {
          float bv = bias[n];
#pragma unroll
          for (int j = 0; j < 4; ++j)
            ((float*)Cout)[(size_t)(m0 + j) * 1024 + n] = acc[mf][nf][j] + bv;
        }
      }
  }
}

// ---------------- fused attention: 1 block per bh, 11 waves (r12/r15 proven) ----------
__global__ __launch_bounds__(704, 3) void k_attn(
    const bf16* __restrict__ qkv, const bf16* __restrict__ vT,
    const bf16* __restrict__ w1t_g, const bf16* __restrict__ w2t_g,
    const float* __restrict__ maskbias, const float* __restrict__ xianT,
    const float* __restrict__ b1, const float* __restrict__ b2,
    bf16* __restrict__ aout) {
  __shared__ __align__(16) char smem[160448];
  bf16* VTs = (bf16*)smem;
  bf16* Ks  = (bf16*)(smem + 49152);
  bf16* AQs = (bf16*)(smem + 49152);
  bf16* Pw0 = (bf16*)(smem + 94208);
  bf16* W1T = (bf16*)(smem + 128000);
  bf16* H1s = (bf16*)(smem + 128000);
  bf16* W2T = (bf16*)(smem + 144384);
  float* biasL = (float*)(smem + 158720);
  float* b1L = (float*)(smem + 159744);
  float* b2L = (float*)(smem + 160000);

  const int tid = threadIdx.x, lane = tid & 63, w = tid >> 6;  // w: 0..10
  const int l15 = lane & 15, l4 = lane >> 4;
  const int i0 = blockIdx.x;
  const int bh = (i0 & 7) * 256 + (i0 >> 3);   // XCD swizzle
  const int b = bh >> 3, h = bh & 7;
  const int rq = w * 16;
  const int pr12 = l15 % 12;

  bf16x8 qf[4];
  {
    int qrow = rq + l15; if (qrow > 163) qrow = 163;
    const bf16* qbase = qkv + (size_t)(b * 164 + qrow) * 3072 + h * 128;
#pragma unroll
    for (int kk = 0; kk < 4; ++kk)
      qf[kk] = *(const bf16x8*)(qbase + kk * 32 + l4 * 8);
  }

  // ---- stage K + bias only (sync0 drains just these) ----
  for (int c = w; c < 41; c += 11) {
    int blk = c * 64 + lane;
    int r = blk >> 4, sl = blk & 15;
    int kb = sl ^ (r & 7);
    gl_lds16(qkv + (size_t)(b * 164 + r) * 3072 + 1024 + h * 128 + kb * 8, (char*)Ks + c * 1024);
  }
  if (w == 10 && lane < 48)
    gl_lds16(maskbias + b * 192 + lane * 4, (char*)biasL);
  if (tid < 192) {
    int r = 164 + (tid >> 4), sl = tid & 15;
    ((int4*)Ks)[r * 16 + sl] = make_int4(0, 0, 0, 0);
  }
  if (tid < 64) b1L[tid] = (tid < 50) ? b1[tid] : 0.f;
  else if (tid < 176) { int c = tid - 64; b2L[c] = (c < 100) ? b2[c] : 0.f; }
  __syncthreads();  // sync0: K + bias landed

  // ---- issue V + W staging now; they fly under QK, drain at sync1 ----
  for (int c = w; c < 48; c += 11) {
    int blk = c * 64 + lane;
    int dh = blk / 24, sl = blk % 24;
    int kb = sl - (dh % 24); if (kb < 0) kb += 24;
    gl_lds16(vT + ((size_t)bh * 128 + dh) * JP + kb * 8, (char*)VTs + c * 1024);
  }
  for (int c = w; c < 16; c += 11)
    gl_lds16(w1t_g + c * 512 + lane * 8, (char*)W1T + c * 1024);
  for (int c = w; c < 14; c += 11)
    gl_lds16(w2t_g + c * 512 + lane * 8, (char*)W2T + c * 1024);

  constexpr float SC = 0.03125f;
  f32x4 s[11];
#pragma unroll
  for (int nt = 0; nt < 11; ++nt) {
    f32x4 acc = f32x4{0.f, 0.f, 0.f, 0.f};
#pragma unroll
    for (int kk = 0; kk < 4; ++kk) {
      bf16x8 kf = *(const bf16x8*)&Ks[sw16(nt * 16 + l15, kk * 4 + l4)];
      acc = __builtin_amdgcn_mfma_f32_16x16x32_bf16(kf, qf[kk], acc, 0, 0, 0);
    }
    f32x4 bv = *(const f32x4*)&biasL[nt * 16 + l4 * 4];
#pragma unroll
    for (int j = 0; j < 4; ++j) acc[j] = acc[j] * SC + bv[j];
    s[nt] = acc;
  }
  __syncthreads();  // sync1: K reads done -> AQ may overlay; V/W landed

  if (w < 7) {
    int q = rq + l15;
#pragma unroll
    for (int nt = 0; nt < 8; ++nt) {
#pragma unroll
      for (int pr = 0; pr < 2; ++pr) {
        int k0 = nt * 16 + l4 * 4 + pr * 2;
        float v0 = (q < 100 && k0 < 100)     ? fmaxf(s[nt][pr * 2], 0.f)     : 0.f;
        float v1 = (q < 100 && k0 + 1 < 100) ? fmaxf(s[nt][pr * 2 + 1], 0.f) : 0.f;
        bf16x2 pv; pv[0] = (bf16)v0; pv[1] = (bf16)v1;
        *(bf16x2*)&AQs[sw16(q, k0 >> 3) + (k0 & 7)] = pv;
      }
    }
  }
  __syncthreads();

  f32x4 a1[3];
#pragma unroll
  for (int it = 0; it < 3; ++it) {
    int t = w + it * 11;
    f32x4 acc = f32x4{0.f, 0.f, 0.f, 0.f};
    if (t < 28) {
      int qs = t >> 2, ct = t & 3;
#pragma unroll
      for (int kk = 0; kk < 4; ++kk) {
        bf16x8 wf = *(const bf16x8*)&W1T[sw16(ct * 16 + l15, kk * 4 + l4)];
        bf16x8 af = *(const bf16x8*)&AQs[sw16(qs * 16 + l15, kk * 4 + l4)];
        acc = __builtin_amdgcn_mfma_f32_16x16x32_bf16(wf, af, acc, 0, 0, 0);
      }
    }
    a1[it] = acc;
  }
  __syncthreads();
#pragma unroll
  for (int it = 0; it < 3; ++it) {
    int t = w + it * 11;
    if (t < 28) {
      int qs = t >> 2, ct = t & 3;
      int qrow = qs * 16 + l15;
#pragma unroll
      for (int pr = 0; pr < 2; ++pr) {
        int c0 = ct * 16 + l4 * 4 + pr * 2;
        float v0 = (c0 < 50)     ? fmaxf(a1[it][pr * 2] + b1L[c0], 0.f)         : 0.f;
        float v1 = (c0 + 1 < 50) ? fmaxf(a1[it][pr * 2 + 1] + b1L[c0 + 1], 0.f) : 0.f;
        bf16x2 pv; pv[0] = (bf16)v0; pv[1] = (bf16)v1;
        *(bf16x2*)&H1s[sw8(qrow, c0 >> 3) + (c0 & 7)] = pv;
      }
    }
  }
  __syncthreads();

  if (w < 7) {
    int q = rq + l15;
#pragma unroll
    for (int nt2 = 0; nt2 < 7; ++nt2) {
      f32x4 acc = f32x4{0.f, 0.f, 0.f, 0.f};
#pragma unroll
      for (int kk = 0; kk < 2; ++kk) {
        bf16x8 wf = *(const bf16x8*)&W2T[sw8(nt2 * 16 + l15, kk * 4 + l4)];
        bf16x8 hf = *(const bf16x8*)&H1s[sw8(rq + l15, kk * 4 + l4)];
        acc = __builtin_amdgcn_mfma_f32_16x16x32_bf16(wf, hf, acc, 0, 0, 0);
      }
#pragma unroll
      for (int j = 0; j < 4; ++j) {
        int jp = nt2 * 16 + l4 * 4 + j;
        if (jp < 100 && q < 100) {
          float lv = fmaxf(acc[j] + b2L[jp], 0.f);
          s[nt2][j] += xianT[((size_t)b * 100 + jp) * 112 + q] * lv;
        }
      }
    }
  }

  float mx = -__FLT_MAX__;
#pragma unroll
  for (int nt = 0; nt < 11; ++nt)
#pragma unroll
    for (int j = 0; j < 4; ++j) mx = fmaxf(mx, s[nt][j]);
  mx = fmaxf(mx, __shfl_xor(mx, 16));
  mx = fmaxf(mx, __shfl_xor(mx, 32));
  float sum = 0.f;
#pragma unroll
  for (int nt = 0; nt < 11; ++nt)
#pragma unroll
    for (int j = 0; j < 4; ++j) { float e = __expf(s[nt][j] - mx); s[nt][j] = e; sum += e; }
  sum += __shfl_xor(sum, 16);
  sum += __shfl_xor(sum, 32);
  float rinv = 1.f / sum;

  bf16x2 pp[11][2];
#pragma unroll
  for (int nt = 0; nt < 11; ++nt)
#pragma unroll
    for (int pr = 0; pr < 2; ++pr) {
      bf16x2 pv;
      pv[0] = (bf16)(s[nt][pr * 2] * rinv);
      pv[1] = (bf16)(s[nt][pr * 2 + 1] * rinv);
      pp[nt][pr] = pv;
    }

  bf16* PwB = Pw0 + w * 1536;
  f32x4 o[8];
#pragma unroll
  for (int i = 0; i < 8; ++i) o[i] = f32x4{0.f, 0.f, 0.f, 0.f};
  int vmr[8];
#pragma unroll
  for (int i = 0; i < 8; ++i) vmr[i] = (i * 16 + l15) % 24;
#pragma unroll
  for (int hh = 0; hh < 2; ++hh) {
#pragma unroll
    for (int nn = 0; nn < 6; ++nn) {
      int nt = hh * 6 + nn;
      if (nt < 11) {
        int slot = nn * 2 + (l4 >> 1);
        int rs = slot + pr12; if (rs >= 12) rs -= 12;
#pragma unroll
        for (int pr = 0; pr < 2; ++pr)
          *(bf16x2*)&PwB[l15 * 96 + rs * 8 + (l4 & 1) * 4 + pr * 2] = pp[nt][pr];
      }
    }
#pragma unroll
    for (int kk2 = 0; kk2 < 3; ++kk2) {
      int rs = kk2 * 4 + l4 + pr12; if (rs >= 12) rs -= 12;
      bf16x8 af = *(const bf16x8*)&PwB[l15 * 96 + rs * 8];
#pragma unroll
      for (int i = 0; i < 8; ++i) {
        int sb = 12 * hh + kk2 * 4 + l4 + vmr[i]; if (sb >= 24) sb -= 24;
        bf16x8 bb = *(const bf16x8*)&VTs[(i * 16 + l15) * 192 + sb * 8];
        o[i] = __builtin_amdgcn_mfma_f32_16x16x32_bf16(af, bb, o[i], 0, 0, 0);
      }
    }
  }

#pragma unroll
  for (int i = 0; i < 8; ++i) {
    int dh = i * 16 + l15;
#pragma unroll
    for (int j = 0; j < 4; ++j) {
      int q = rq + l4 * 4 + j;
      if (q < 164)
        aout[(size_t)(b * 164 + q) * 1024 + h * 128 + dh] = (bf16)o[i][j];
    }
  }
}

// ---------------- launch ----------------
extern "C" void kernel_launch(void* const* d_in, const int* in_sizes, int n_in,
                              void* d_out, int out_size, void* d_ws, size_t ws_size,
                              hipStream_t stream) {
  const float* x    = (const float*)d_in[0];
  const void* mask  = (const void*)d_in[1];
  const float* xian = (const float*)d_in[2];
  const float* Wqkv = (const float*)d_in[3];
  const float* W1   = (const float*)d_in[4];
  const float* b1   = (const float*)d_in[5];
  const float* W2   = (const float*)d_in[6];
  const float* b2   = (const float*)d_in[7];
  const float* Wout = (const float*)d_in[8];
  const float* bout = (const float*)d_in[9];
  float* out = (float*)d_out;
  char* ws = (char*)d_ws;

  // workspace layout (bytes)
  bf16* xb    = (bf16*)(ws);                    // [41984][1024]
  bf16* wqkvT = (bf16*)(ws + 85983232ULL);      // [3072][1024]
  bf16* woutT = (bf16*)(ws + 92274688ULL);      // [1024][1024]
  bf16* qkvb  = (bf16*)(ws + 94371840ULL);      // [41984][3072]
  bf16* vTb   = (bf16*)(ws + 352321536ULL);     // [2048][128][192]
  bf16* aoutb = (bf16*)(ws + 452984832ULL);     // [41984][1024]
  int*   mmode    = (int*)(ws + 1024);
  bf16*  w1t_g    = (bf16*)(ws + 4096);
  bf16*  w2t_g    = (bf16*)(ws + 20480);
  float* maskbias = (float*)(ws + 36864);
  float* xianTp   = (float*)(ws + 262144);

  k_cvt_bf16<<<2048, 256, 0, stream>>>(x, xb, Mm * 1024);
  k_transpose_cvt<<<dim3(96, 32), 256, 0, stream>>>(Wqkv, wqkvT, 1024, 3072);
  k_transpose_cvt<<<dim3(32, 32), 256, 0, stream>>>(Wout, woutT, 1024, 1024);
  k_gemm<0><<<1968, 512, 0, stream>>>(xb, wqkvT, (void*)qkvb, nullptr, vTb);
  k_maskdet<<<1, 256, 0, stream>>>((const unsigned char*)mask, mmode);
  k_prep_w<<<1, 256, 0, stream>>>(W1, W2, w1t_g, w2t_g);
  k_maskbias<<<256, 192, 0, stream>>>(mask, mmode, maskbias);
  k_xianT<<<dim3(16, 256), 256, 0, stream>>>(xian, xianTp);
  k_attn<<<2048, 704, 0, stream>>>(qkvb, vTb, w1t_g, w2t_g, maskbias, xianTp,
                                   b1, b2, aoutb);
  k_gemm<1><<<656, 512, 0, stream>>>(aoutb, woutT, (void*)out, bout, nullptr);
}

// Round 17
// 725.999 us; speedup vs baseline: 1.0547x; 1.0547x over previous
//
#include <hip/hip_runtime.h>
#include <hip/hip_bf16.h>
#include <cstdint>
#include <cstddef>

typedef __bf16 bf16;
typedef __attribute__((ext_vector_type(8))) __bf16 bf16x8;
typedef __attribute__((ext_vector_type(2))) __bf16 bf16x2;
typedef __attribute__((ext_vector_type(4))) __bf16 bf16x4;
typedef __attribute__((ext_vector_type(4))) float f32x4;

#define DEVI __device__ __forceinline__

constexpr int Bb = 256, Nn = 164, NKk = 100;
constexpr int Mm = Bb * Nn;   // 41984 = 164 * 256
constexpr int JP = 192;

DEVI void gl_lds16(const void* g, void* l) {
  __builtin_amdgcn_global_load_lds(
      (const __attribute__((address_space(1))) void*)g,
      (__attribute__((address_space(3))) void*)l, 16, 0, 0);
}

DEVI int sw16(int row, int kb) { return row * 128 + ((kb ^ (row & 7)) * 8); }
DEVI int sw8(int row, int kb)  { return row * 64 + ((kb ^ (row & 7)) * 8); }

DEVI void barrier_raw() {
  asm volatile("" ::: "memory");
  __builtin_amdgcn_s_barrier();
  asm volatile("" ::: "memory");
}
DEVI void vm0_barrier() {
  asm volatile("s_waitcnt vmcnt(0)" ::: "memory");
  __builtin_amdgcn_s_barrier();
  asm volatile("" ::: "memory");
}

// ---------------- convert f32 -> bf16 (flat) ----------------
__global__ void k_cvt_bf16(const float* __restrict__ in, bf16* __restrict__ out, int n) {
  int stride = gridDim.x * blockDim.x;
  for (int i = blockIdx.x * blockDim.x + threadIdx.x; i < (n >> 2); i += stride) {
    float4 v = ((const float4*)in)[i];
    bf16x4 o;
    o[0] = (bf16)v.x; o[1] = (bf16)v.y; o[2] = (bf16)v.z; o[3] = (bf16)v.w;
    ((bf16x4*)out)[i] = o;
  }
}

// ---------------- mask dtype detection ----------------
__global__ void k_maskdet(const unsigned char* __restrict__ m, int* __restrict__ mode) {
  __shared__ int sbyte, sodd;
  if (threadIdx.x == 0) { sbyte = 0; sodd = 0; }
  __syncthreads();
  for (int i = threadIdx.x; i < Mm; i += 256)
    if ((i & 3) && m[i]) sbyte = 1;
  __syncthreads();
  if (sbyte == 0) {
    const int* m32 = (const int*)m;
    for (int i = 1 + 2 * (int)threadIdx.x; i < Mm; i += 512)
      if (m32[i] != 0) sodd = 1;
  }
  __syncthreads();
  if (threadIdx.x == 0) *mode = sbyte ? 1 : (sodd ? 0 : 2);
}

// ---------------- prep: W1T/W2T swizzled bf16 LDS-images ----------------
__global__ void k_prep_w(const float* __restrict__ W1, const float* __restrict__ W2,
                         bf16* __restrict__ w1t, bf16* __restrict__ w2t) {
  int tid = threadIdx.x;
  int4 z = make_int4(0, 0, 0, 0);
  for (int i = tid; i < 1024; i += 256) ((int4*)w1t)[i] = z;  // 16384 B
  for (int i = tid; i < 896;  i += 256) ((int4*)w2t)[i] = z;  // 14336 B
  __syncthreads();
  for (int idx = tid; idx < 5000; idx += 256) {  // W1 [100][50] -> rows=c cols=k
    int k = idx / 50, c = idx % 50;
    w1t[sw16(c, k >> 3) + (k & 7)] = (bf16)W1[idx];
  }
  for (int idx = tid; idx < 5000; idx += 256) {  // W2 [50][100] -> rows=jp cols=c
    int c = idx / 100, jp = idx % 100;
    w2t[sw8(jp, c >> 3) + (c & 7)] = (bf16)W2[idx];
  }
}

// ---------------- prep: mask -> additive bias rows [256][192] f32 ----------------
__global__ void k_maskbias(const void* __restrict__ maskp, const int* __restrict__ mode,
                           float* __restrict__ mb) {
  int b = blockIdx.x, col = threadIdx.x;  // 192 threads
  int mmode = *mode;
  float v;
  if (col < NKk) v = 0.f;
  else if (col < 164) {
    int mi = b * 164 + col;
    long long m = (mmode == 1) ? (long long)((const unsigned char*)maskp)[mi]
                : (mmode == 0) ? (long long)((const int*)maskp)[mi]
                               : ((const long long*)maskp)[mi];
    v = m ? -__FLT_MAX__ : 0.f;
  } else v = -__FLT_MAX__;
  mb[b * 192 + col] = v;
}

// ---------------- prep: xian [b][gi][jp] -> xianT [b][jp][112-stride gi] ----------------
__global__ void k_xianT(const float* __restrict__ xian, float* __restrict__ xT) {
  __shared__ float t[32][33];
  int b = blockIdx.y;
  int gt = blockIdx.x & 3, jt = blockIdx.x >> 2;
  int tx = threadIdx.x & 31, ty = threadIdx.x >> 5;
#pragma unroll
  for (int i = 0; i < 4; ++i) {
    int gi = gt * 32 + ty + i * 8, jp = jt * 32 + tx;
    t[ty + i * 8][tx] = (gi < 100 && jp < 100) ? xian[((size_t)b * 100 + gi) * 100 + jp] : 0.f;
  }
  __syncthreads();
#pragma unroll
  for (int i = 0; i < 4; ++i) {
    int jp = jt * 32 + ty + i * 8, gi = gt * 32 + tx;
    if (jp < 100 && gi < 112)
      xT[((size_t)b * 100 + jp) * 112 + gi] = t[tx][ty + i * 8];
  }
}

// ---------------- transpose + convert: (R x C f32) -> (C x R bf16) ----------------
__global__ void k_transpose_cvt(const float* __restrict__ in, bf16* __restrict__ out,
                                int R, int C) {
  __shared__ float tile[32][33];
  int c0 = blockIdx.x * 32, r0 = blockIdx.y * 32;
  int tx = threadIdx.x & 31, ty = threadIdx.x >> 5;
#pragma unroll
  for (int i = 0; i < 4; ++i) {
    int r = ty + i * 8;
    tile[r][tx] = in[(size_t)(r0 + r) * C + c0 + tx];
  }
  __syncthreads();
#pragma unroll
  for (int i = 0; i < 4; ++i) {
    int rr = ty + i * 8;
    out[(size_t)(c0 + rr) * R + r0 + tx] = (bf16)tile[tx][rr];
  }
}

// ======== 256x256 / BK=64 / 8-wave pipelined GEMM — 2 phases x 32 MFMA per tile ========
// C(MxN) = A(MxK) * Bt(NxK)^T, K=1024.
// MODE 0: C bf16 ld 3072; N-tiles with tileN>=2048 (V region) written TRANSPOSED
//         into vT [bh][dh][192] via LDS bounce (fused k_vT).
// MODE 1: C f32 + bias, ld 1024.
template <int MODE>
__global__ __launch_bounds__(512, 2) void k_gemm(const bf16* __restrict__ A,
                                                 const bf16* __restrict__ Bt,
                                                 void* __restrict__ Cout,
                                                 const float* __restrict__ bias,
                                                 bf16* __restrict__ vTout) {
  constexpr int K = 1024;
  constexpr int NT = 16;
  __shared__ __align__(16) char smem[131072];

  const int tid = threadIdx.x, lane = tid & 63, w = tid >> 6;
  const int l15 = lane & 15, l4 = lane >> 4;
  const int wm = w >> 2, wn = w & 3;

  const int nbx = (MODE == 0) ? 12 : 4;
  const int lin = blockIdx.x;
  const int cpx = gridDim.x >> 3;
  const int swz = (lin & 7) * cpx + (lin >> 3);
  const int tileM = (swz / nbx) * 256, tileN = (swz % nbx) * 256;

  size_t aoff[4], boff[4]; int loff[4];
#pragma unroll
  for (int li = 0; li < 4; ++li) {
    int idx = li * 512 + tid;
    int row = idx >> 3, sl = idx & 7;
    int kb = sl ^ (row & 7);
    aoff[li] = (size_t)(tileM + row) * K + kb * 8;
    boff[li] = (size_t)(tileN + row) * K + kb * 8;
    loff[li] = idx * 16;
  }

  f32x4 acc[8][4];
#pragma unroll
  for (int mf = 0; mf < 8; ++mf)
#pragma unroll
    for (int nf = 0; nf < 4; ++nf) acc[mf][nf] = f32x4{0.f, 0.f, 0.f, 0.f};

#pragma unroll
  for (int li = 0; li < 4; ++li) {
    gl_lds16(A + aoff[li], smem + loff[li]);
    gl_lds16(Bt + boff[li], smem + 65536 + loff[li]);
  }

  for (int t = 0; t < NT; ++t) {
    const int coff = (t & 1) << 15;
    const char* Ac = smem + coff;
    const char* Bc = smem + 65536 + coff;
    char* An = smem + (coff ^ 32768);
    char* Bn = smem + 65536 + (coff ^ 32768);
    const int kadd = (t + 1) * 64;
    const bool st = (t + 1) < NT;

    vm0_barrier();

    bf16x8 bfr[4][2];
#pragma unroll
    for (int nf = 0; nf < 4; ++nf) {
      int row = wn * 64 + nf * 16 + l15;
#pragma unroll
      for (int kk = 0; kk < 2; ++kk)
        bfr[nf][kk] = *(const bf16x8*)(Bc + row * 128 + (((kk * 4 + l4) ^ (row & 7)) * 16));
    }

#pragma unroll
    for (int ph = 0; ph < 2; ++ph) {
      // prefetch tile t+1: A in ph0, B in ph1
      if (st) {
        if (ph == 0) {
#pragma unroll
          for (int li = 0; li < 4; ++li)
            gl_lds16(A + aoff[li] + kadd, An + loff[li]);
        } else {
#pragma unroll
          for (int li = 0; li < 4; ++li)
            gl_lds16(Bt + boff[li] + kadd, Bn + loff[li]);
        }
      }
      // A fragments for this phase's four M-frags
      bf16x8 af[4][2];
#pragma unroll
      for (int mi = 0; mi < 4; ++mi) {
        int row = wm * 128 + (ph * 4 + mi) * 16 + l15;
#pragma unroll
        for (int kk = 0; kk < 2; ++kk)
          af[mi][kk] = *(const bf16x8*)(Ac + row * 128 + (((kk * 4 + l4) ^ (row & 7)) * 16));
      }
      __builtin_amdgcn_s_setprio(1);
#pragma unroll
      for (int mi = 0; mi < 4; ++mi)
#pragma unroll
        for (int nf = 0; nf < 4; ++nf)
#pragma unroll
          for (int kk = 0; kk < 2; ++kk)
            acc[ph * 4 + mi][nf] = __builtin_amdgcn_mfma_f32_16x16x32_bf16(
                af[mi][kk], bfr[nf][kk], acc[ph * 4 + mi][nf], 0, 0, 0);
      __builtin_amdgcn_s_setprio(0);
      barrier_raw();
    }
  }

  if (MODE == 0 && tileN >= 2048) {
    const int h0 = (tileN - 2048) >> 7;
    bf16* Et = (bf16*)smem;
#pragma unroll
    for (int nh = 0; nh < 2; ++nh) {
      barrier_raw();
      if ((wn >> 1) == nh) {
#pragma unroll
        for (int mf = 0; mf < 8; ++mf)
#pragma unroll
          for (int nf = 0; nf < 4; ++nf) {
            int nr = (wn & 1) * 64 + nf * 16 + l15;
            int mr = wm * 128 + mf * 16 + l4 * 4;
            bf16x4 pv;
#pragma unroll
            for (int j = 0; j < 4; ++j) pv[j] = (bf16)acc[mf][nf][j];
            *(bf16x4*)&Et[nr * 264 + mr] = pv;
          }
      }
      barrier_raw();
#pragma unroll
      for (int r8 = 0; r8 < 8; ++r8) {
        int idx = r8 * 512 + tid;
        int nr = idx >> 5, m8 = (idx & 31) * 8;
        bf16x8 v = *(const bf16x8*)&Et[nr * 264 + m8];
        int m = tileM + m8;
        int b = m / 164, j = m - b * 164;
        if (j + 7 < 164) {
          size_t base = ((size_t)(b * 8 + h0 + nh) * 128 + nr) * JP + j;
          bf16x4 lo, hi;
#pragma unroll
          for (int e = 0; e < 4; ++e) { lo[e] = v[e]; hi[e] = v[e + 4]; }
          *(bf16x4*)&vTout[base] = lo;
          *(bf16x4*)&vTout[base + 4] = hi;
        } else {
#pragma unroll
          for (int e = 0; e < 8; ++e) {
            int me = m + e; int be = me / 164, je = me - be * 164;
            vTout[((size_t)(be * 8 + h0 + nh) * 128 + nr) * JP + je] = v[e];
          }
        }
      }
    }
  } else {
#pragma unroll
    for (int mf = 0; mf < 8; ++mf)
#pragma unroll
      for (int nf = 0; nf < 4; ++nf) {
        int m0 = tileM + wm * 128 + mf * 16 + l4 * 4;
        int n = tileN + wn * 64 + nf * 16 + l15;
        if (MODE == 0) {
#pragma unroll
          for (int j = 0; j < 4; ++j)
            ((bf16*)Cout)[(size_t)(m0 + j) * 3072 + n] = (bf16)acc[mf][nf][j];
        } else {
          float bv = bias[n];
#pragma unroll
          for (int j = 0; j < 4; ++j)
            ((float*)Cout)[(size_t)(m0 + j) * 1024 + n] = acc[mf][nf][j] + bv;
        }
      }
  }
}

// ---------------- fused attention: 1 block per bh, 11 waves (r12/r15 proven) ----------
__global__ __launch_bounds__(704, 3) void k_attn(
    const bf16* __restrict__ qkv, const bf16* __restrict__ vT,
    const bf16* __restrict__ w1t_g, const bf16* __restrict__ w2t_g,
    const float* __restrict__ maskbias, const float* __restrict__ xianT,
    const float* __restrict__ b1, const float* __restrict__ b2,
    bf16* __restrict__ aout) {
  __shared__ __align__(16) char smem[160448];
  bf16* VTs = (bf16*)smem;
  bf16* Ks  = (bf16*)(smem + 49152);
  bf16* AQs = (bf16*)(smem + 49152);
  bf16* Pw0 = (bf16*)(smem + 94208);
  bf16* W1T = (bf16*)(smem + 128000);
  bf16* H1s = (bf16*)(smem + 128000);
  bf16* W2T = (bf16*)(smem + 144384);
  float* biasL = (float*)(smem + 158720);
  float* b1L = (float*)(smem + 159744);
  float* b2L = (float*)(smem + 160000);

  const int tid = threadIdx.x, lane = tid & 63, w = tid >> 6;  // w: 0..10
  const int l15 = lane & 15, l4 = lane >> 4;
  const int i0 = blockIdx.x;
  const int bh = (i0 & 7) * 256 + (i0 >> 3);   // XCD swizzle
  const int b = bh >> 3, h = bh & 7;
  const int rq = w * 16;
  const int pr12 = l15 % 12;

  bf16x8 qf[4];
  {
    int qrow = rq + l15; if (qrow > 163) qrow = 163;
    const bf16* qbase = qkv + (size_t)(b * 164 + qrow) * 3072 + h * 128;
#pragma unroll
    for (int kk = 0; kk < 4; ++kk)
      qf[kk] = *(const bf16x8*)(qbase + kk * 32 + l4 * 8);
  }

  // ---- stage K + bias only (sync0 drains just these) ----
  for (int c = w; c < 41; c += 11) {
    int blk = c * 64 + lane;
    int r = blk >> 4, sl = blk & 15;
    int kb = sl ^ (r & 7);
    gl_lds16(qkv + (size_t)(b * 164 + r) * 3072 + 1024 + h * 128 + kb * 8, (char*)Ks + c * 1024);
  }
  if (w == 10 && lane < 48)
    gl_lds16(maskbias + b * 192 + lane * 4, (char*)biasL);
  if (tid < 192) {
    int r = 164 + (tid >> 4), sl = tid & 15;
    ((int4*)Ks)[r * 16 + sl] = make_int4(0, 0, 0, 0);
  }
  if (tid < 64) b1L[tid] = (tid < 50) ? b1[tid] : 0.f;
  else if (tid < 176) { int c = tid - 64; b2L[c] = (c < 100) ? b2[c] : 0.f; }
  __syncthreads();  // sync0: K + bias landed

  // ---- issue V + W staging now; they fly under QK, drain at sync1 ----
  for (int c = w; c < 48; c += 11) {
    int blk = c * 64 + lane;
    int dh = blk / 24, sl = blk % 24;
    int kb = sl - (dh % 24); if (kb < 0) kb += 24;
    gl_lds16(vT + ((size_t)bh * 128 + dh) * JP + kb * 8, (char*)VTs + c * 1024);
  }
  for (int c = w; c < 16; c += 11)
    gl_lds16(w1t_g + c * 512 + lane * 8, (char*)W1T + c * 1024);
  for (int c = w; c < 14; c += 11)
    gl_lds16(w2t_g + c * 512 + lane * 8, (char*)W2T + c * 1024);

  constexpr float SC = 0.03125f;
  f32x4 s[11];
#pragma unroll
  for (int nt = 0; nt < 11; ++nt) {
    f32x4 acc = f32x4{0.f, 0.f, 0.f, 0.f};
#pragma unroll
    for (int kk = 0; kk < 4; ++kk) {
      bf16x8 kf = *(const bf16x8*)&Ks[sw16(nt * 16 + l15, kk * 4 + l4)];
      acc = __builtin_amdgcn_mfma_f32_16x16x32_bf16(kf, qf[kk], acc, 0, 0, 0);
    }
    f32x4 bv = *(const f32x4*)&biasL[nt * 16 + l4 * 4];
#pragma unroll
    for (int j = 0; j < 4; ++j) acc[j] = acc[j] * SC + bv[j];
    s[nt] = acc;
  }
  __syncthreads();  // sync1: K reads done -> AQ may overlay; V/W landed

  if (w < 7) {
    int q = rq + l15;
#pragma unroll
    for (int nt = 0; nt < 8; ++nt) {
#pragma unroll
      for (int pr = 0; pr < 2; ++pr) {
        int k0 = nt * 16 + l4 * 4 + pr * 2;
        float v0 = (q < 100 && k0 < 100)     ? fmaxf(s[nt][pr * 2], 0.f)     : 0.f;
        float v1 = (q < 100 && k0 + 1 < 100) ? fmaxf(s[nt][pr * 2 + 1], 0.f) : 0.f;
        bf16x2 pv; pv[0] = (bf16)v0; pv[1] = (bf16)v1;
        *(bf16x2*)&AQs[sw16(q, k0 >> 3) + (k0 & 7)] = pv;
      }
    }
  }
  __syncthreads();

  f32x4 a1[3];
#pragma unroll
  for (int it = 0; it < 3; ++it) {
    int t = w + it * 11;
    f32x4 acc = f32x4{0.f, 0.f, 0.f, 0.f};
    if (t < 28) {
      int qs = t >> 2, ct = t & 3;
#pragma unroll
      for (int kk = 0; kk < 4; ++kk) {
        bf16x8 wf = *(const bf16x8*)&W1T[sw16(ct * 16 + l15, kk * 4 + l4)];
        bf16x8 af = *(const bf16x8*)&AQs[sw16(qs * 16 + l15, kk * 4 + l4)];
        acc = __builtin_amdgcn_mfma_f32_16x16x32_bf16(wf, af, acc, 0, 0, 0);
      }
    }
    a1[it] = acc;
  }
  __syncthreads();
#pragma unroll
  for (int it = 0; it < 3; ++it) {
    int t = w + it * 11;
    if (t < 28) {
      int qs = t >> 2, ct = t & 3;
      int qrow = qs * 16 + l15;
#pragma unroll
      for (int pr = 0; pr < 2; ++pr) {
        int c0 = ct * 16 + l4 * 4 + pr * 2;
        float v0 = (c0 < 50)     ? fmaxf(a1[it][pr * 2] + b1L[c0], 0.f)         : 0.f;
        float v1 = (c0 + 1 < 50) ? fmaxf(a1[it][pr * 2 + 1] + b1L[c0 + 1], 0.f) : 0.f;
        bf16x2 pv; pv[0] = (bf16)v0; pv[1] = (bf16)v1;
        *(bf16x2*)&H1s[sw8(qrow, c0 >> 3) + (c0 & 7)] = pv;
      }
    }
  }
  __syncthreads();

  if (w < 7) {
    int q = rq + l15;
#pragma unroll
    for (int nt2 = 0; nt2 < 7; ++nt2) {
      f32x4 acc = f32x4{0.f, 0.f, 0.f, 0.f};
#pragma unroll
      for (int kk = 0; kk < 2; ++kk) {
        bf16x8 wf = *(const bf16x8*)&W2T[sw8(nt2 * 16 + l15, kk * 4 + l4)];
        bf16x8 hf = *(const bf16x8*)&H1s[sw8(rq + l15, kk * 4 + l4)];
        acc = __builtin_amdgcn_mfma_f32_16x16x32_bf16(wf, hf, acc, 0, 0, 0);
      }
#pragma unroll
      for (int j = 0; j < 4; ++j) {
        int jp = nt2 * 16 + l4 * 4 + j;
        if (jp < 100 && q < 100) {
          float lv = fmaxf(acc[j] + b2L[jp], 0.f);
          s[nt2][j] += xianT[((size_t)b * 100 + jp) * 112 + q] * lv;
        }
      }
    }
  }

  float mx = -__FLT_MAX__;
#pragma unroll
  for (int nt = 0; nt < 11; ++nt)
#pragma unroll
    for (int j = 0; j < 4; ++j) mx = fmaxf(mx, s[nt][j]);
  mx = fmaxf(mx, __shfl_xor(mx, 16));
  mx = fmaxf(mx, __shfl_xor(mx, 32));
  float sum = 0.f;
#pragma unroll
  for (int nt = 0; nt < 11; ++nt)
#pragma unroll
    for (int j = 0; j < 4; ++j) { float e = __expf(s[nt][j] - mx); s[nt][j] = e; sum += e; }
  sum += __shfl_xor(sum, 16);
  sum += __shfl_xor(sum, 32);
  float rinv = 1.f / sum;

  bf16x2 pp[11][2];
#pragma unroll
  for (int nt = 0; nt < 11; ++nt)
#pragma unroll
    for (int pr = 0; pr < 2; ++pr) {
      bf16x2 pv;
      pv[0] = (bf16)(s[nt][pr * 2] * rinv);
      pv[1] = (bf16)(s[nt][pr * 2 + 1] * rinv);
      pp[nt][pr] = pv;
    }

  bf16* PwB = Pw0 + w * 1536;
  f32x4 o[8];
#pragma unroll
  for (int i = 0; i < 8; ++i) o[i] = f32x4{0.f, 0.f, 0.f, 0.f};
  int vmr[8];
#pragma unroll
  for (int i = 0; i < 8; ++i) vmr[i] = (i * 16 + l15) % 24;
#pragma unroll
  for (int hh = 0; hh < 2; ++hh) {
#pragma unroll
    for (int nn = 0; nn < 6; ++nn) {
      int nt = hh * 6 + nn;
      if (nt < 11) {
        int slot = nn * 2 + (l4 >> 1);
        int rs = slot + pr12; if (rs >= 12) rs -= 12;
#pragma unroll
        for (int pr = 0; pr < 2; ++pr)
          *(bf16x2*)&PwB[l15 * 96 + rs * 8 + (l4 & 1) * 4 + pr * 2] = pp[nt][pr];
      }
    }
#pragma unroll
    for (int kk2 = 0; kk2 < 3; ++kk2) {
      int rs = kk2 * 4 + l4 + pr12; if (rs >= 12) rs -= 12;
      bf16x8 af = *(const bf16x8*)&PwB[l15 * 96 + rs * 8];
#pragma unroll
      for (int i = 0; i < 8; ++i) {
        int sb = 12 * hh + kk2 * 4 + l4 + vmr[i]; if (sb >= 24) sb -= 24;
        bf16x8 bb = *(const bf16x8*)&VTs[(i * 16 + l15) * 192 + sb * 8];
        o[i] = __builtin_amdgcn_mfma_f32_16x16x32_bf16(af, bb, o[i], 0, 0, 0);
      }
    }
  }

#pragma unroll
  for (int i = 0; i < 8; ++i) {
    int dh = i * 16 + l15;
#pragma unroll
    for (int j = 0; j < 4; ++j) {
      int q = rq + l4 * 4 + j;
      if (q < 164)
        aout[(size_t)(b * 164 + q) * 1024 + h * 128 + dh] = (bf16)o[i][j];
    }
  }
}

// ---------------- launch ----------------
extern "C" void kernel_launch(void* const* d_in, const int* in_sizes, int n_in,
                              void* d_out, int out_size, void* d_ws, size_t ws_size,
                              hipStream_t stream) {
  const float* x    = (const float*)d_in[0];
  const void* mask  = (const void*)d_in[1];
  const float* xian = (const float*)d_in[2];
  const float* Wqkv = (const float*)d_in[3];
  const float* W1   = (const float*)d_in[4];
  const float* b1   = (const float*)d_in[5];
  const float* W2   = (const float*)d_in[6];
  const float* b2   = (const float*)d_in[7];
  const float* Wout = (const float*)d_in[8];
  const float* bout = (const float*)d_in[9];
  float* out = (float*)d_out;
  char* ws = (char*)d_ws;

  // workspace layout (bytes)
  bf16* xb    = (bf16*)(ws);                    // [41984][1024]
  bf16* wqkvT = (bf16*)(ws + 85983232ULL);      // [3072][1024]
  bf16* woutT = (bf16*)(ws + 92274688ULL);      // [1024][1024]
  bf16* qkvb  = (bf16*)(ws + 94371840ULL);      // [41984][3072]
  bf16* vTb   = (bf16*)(ws + 352321536ULL);     // [2048][128][192]
  bf16* aoutb = (bf16*)(ws + 452984832ULL);     // [41984][1024]
  int*   mmode    = (int*)(ws + 1024);
  bf16*  w1t_g    = (bf16*)(ws + 4096);
  bf16*  w2t_g    = (bf16*)(ws + 20480);
  float* maskbias = (float*)(ws + 36864);
  float* xianTp   = (float*)(ws + 262144);

  k_cvt_bf16<<<2048, 256, 0, stream>>>(x, xb, Mm * 1024);
  k_transpose_cvt<<<dim3(96, 32), 256, 0, stream>>>(Wqkv, wqkvT, 1024, 3072);
  k_transpose_cvt<<<dim3(32, 32), 256, 0, stream>>>(Wout, woutT, 1024, 1024);
  k_gemm<0><<<1968, 512, 0, stream>>>(xb, wqkvT, (void*)qkvb, nullptr, vTb);
  k_maskdet<<<1, 256, 0, stream>>>((const unsigned char*)mask, mmode);
  k_prep_w<<<1, 256, 0, stream>>>(W1, W2, w1t_g, w2t_g);
  k_maskbias<<<256, 192, 0, stream>>>(mask, mmode, maskbias);
  k_xianT<<<dim3(16, 256), 256, 0, stream>>>(xian, xianTp);
  k_attn<<<2048, 704, 0, stream>>>(qkvb, vTb, w1t_g, w2t_g, maskbias, xianTp,
                                   b1, b2, aoutb);
  k_gemm<1><<<656, 512, 0, stream>>>(aoutb, woutT, (void*)out, bout, nullptr);
}